// Round 14
// baseline (805.307 us; speedup 1.0000x reference)
//
#include <hip/hip_runtime.h>

// ---------------------------------------------------------------------------
// HeteroGATv2Encoder on MI355X (gfx950).
// fp32 in / fp32 out. Merged per-layer bf16 MFMA GEMM (XCD swizzle, LDS XOR
// swizzle, two-pass LDS epilogue + nontemporal C stores). CSR edges + fused
// per-node GAT kernels (2 waves/node, depth-2 prefetch, no-max softmax).
// ---------------------------------------------------------------------------

#define NN 20000      // nodes
#define NE 100000     // edges per relation
#define DH 512        // hidden width (8 heads x 64)
#define DOUT 256

typedef __attribute__((ext_vector_type(8))) short short8;
typedef __attribute__((ext_vector_type(4))) short short4v;
typedef __attribute__((ext_vector_type(4))) float f32x4;
typedef __attribute__((ext_vector_type(4))) unsigned int u32x4;

__device__ __forceinline__ float b2f(unsigned short s) {
    union { unsigned u; float f; } v; v.u = ((unsigned)s) << 16; return v.f;
}
__device__ __forceinline__ unsigned short f2b(float f) {
    unsigned u = __float_as_uint(f);
    u += 0x7FFFu + ((u >> 16) & 1u);   // RNE
    return (unsigned short)(u >> 16);
}
__device__ __forceinline__ void load_lds16(const unsigned short* g, unsigned short* l) {
    __builtin_amdgcn_global_load_lds(
        (const __attribute__((address_space(1))) unsigned int*)g,
        (__attribute__((address_space(3))) unsigned int*)l, 16, 0, 0);
}

// ---------------------------------------------------------------------------
__global__ void cvt_f2b_k(const float* __restrict__ in,
                          unsigned short* __restrict__ out, int n) {
    int i0 = (blockIdx.x * blockDim.x + threadIdx.x) * 8;
    if (i0 >= n) return;
    #pragma unroll
    for (int j = 0; j < 8; j++) out[i0 + j] = f2b(in[i0 + j]);
}

// ---------------------------------------------------------------------------
// Merged transpose+cast: 19 weight matrices in one launch.
// ---------------------------------------------------------------------------
struct TSeg { const float* in; unsigned short* out; int C; };
struct TTable { TSeg s[19]; };

__global__ void transpose_all_k(TTable t) {
    __shared__ float tile[32][33];
    TSeg d = t.s[blockIdx.y];
    int tiles_x = d.C >> 5;
    int nt = tiles_x << 4;
    if ((int)blockIdx.x >= nt) return;
    int bx = blockIdx.x % tiles_x, by = blockIdx.x / tiles_x;
    int c0 = bx * 32, r0 = by * 32;
    int tx = threadIdx.x & 31, ty = threadIdx.x >> 5;
    #pragma unroll
    for (int i = ty; i < 32; i += 8)
        tile[i][tx] = d.in[(size_t)(r0 + i) * d.C + c0 + tx];
    __syncthreads();
    #pragma unroll
    for (int i = ty; i < 32; i += 8)
        d.out[(size_t)(c0 + i) * 512 + r0 + tx] = f2b(tile[tx][i]);
}

// ---------------------------------------------------------------------------
// CSR build (merged over the 3 relations)
// ---------------------------------------------------------------------------
__global__ void count_all_k(const int* __restrict__ ei, int* __restrict__ counts) {
    int i = blockIdx.x * blockDim.x + threadIdx.x;
    if (i >= 3 * NE) return;
    int et = i / NE, idx = i - et * NE;
    int d = ei[(size_t)et * 2 * NE + NE + idx];
    atomicAdd(&counts[et * (NN + 1) + d], 1);
}

__global__ __launch_bounds__(1024)
void scan_par_k(const int* __restrict__ counts, int* __restrict__ offs,
                int* __restrict__ cursor, int n) {
    __shared__ int part[1024];
    const int* c = counts + (size_t)blockIdx.x * (n + 1);
    int* o = offs + (size_t)blockIdx.x * (n + 1);
    int* cu = cursor + (size_t)blockIdx.x * (n + 1);
    int tid = threadIdx.x;
    int per = (n + 1023) / 1024;
    int base = tid * per;
    int lim = min(base + per, n);
    int sum = 0;
    for (int i = base; i < lim; i++) sum += c[i];
    part[tid] = sum;
    __syncthreads();
    #pragma unroll
    for (int off = 1; off < 1024; off <<= 1) {
        int v = (tid >= off) ? part[tid - off] : 0;
        __syncthreads();
        part[tid] += v;
        __syncthreads();
    }
    int run = part[tid] - sum;
    for (int i = base; i < lim; i++) { o[i] = run; cu[i] = run; run += c[i]; }
    if (tid == 1023) { o[n] = part[1023]; cu[n] = part[1023]; }
}

__global__ void scatter_all_k(const int* __restrict__ ei, int* __restrict__ cursor,
                              int* __restrict__ srcs_sorted) {
    int i = blockIdx.x * blockDim.x + threadIdx.x;
    if (i >= 3 * NE) return;
    int et = i / NE, idx = i - et * NE;
    int s = ei[(size_t)et * 2 * NE + idx];
    int d = ei[(size_t)et * 2 * NE + NE + idx];
    int p = atomicAdd(&cursor[et * (NN + 1) + d], 1);
    srcs_sorted[(size_t)et * NE + p] = s;
}

// ---------------------------------------------------------------------------
// Tiled GEMM: XCD swizzle + XOR-swizzled LDS. Epilogue: two 64-row passes
// staged in the (reused) 32KB LDS, then nontemporal coalesced 16B stores
// (C bypasses L2 so the B-panel stays resident per XCD).
// ---------------------------------------------------------------------------
template<int ACT, int SEGL2>
__global__ __launch_bounds__(256)
void gemm_k(const unsigned short* __restrict__ A,
            const unsigned short* __restrict__ Bt,
            const float* __restrict__ lb,
            const float* __restrict__ rb,
            unsigned short* __restrict__ Cb,
            int M, int N, int K, int MT, int NT, int STRIPE) {
    __shared__ __align__(16) unsigned short smem[16384];   // 32 KB exactly
    unsigned short* As = smem;           // 128*64
    unsigned short* Bs = smem + 8192;    // 128*64
    int bid = blockIdx.x;
    int xcd = bid & 7, r = bid >> 3;
    int mtile = xcd * STRIPE + r / NT;
    int ntile = r % NT;
    if (mtile >= MT) return;
    int bm0 = mtile * 128, bn0 = ntile * 128;

    int tid = threadIdx.x;
    int lane = tid & 63, wave = tid >> 6;
    int quad = lane >> 4, l16 = lane & 15;
    int rw = (wave >> 1) * 64, cw = (wave & 1) * 64;
    int rxor = l16 & 7;

    f32x4 acc[4][4];
    #pragma unroll
    for (int mi = 0; mi < 4; mi++)
        #pragma unroll
        for (int ni = 0; ni < 4; ni++) acc[mi][ni] = (f32x4){0.f, 0.f, 0.f, 0.f};

    for (int k0 = 0; k0 < K; k0 += 64) {
        #pragma unroll
        for (int i = 0; i < 4; i++) {
            int f = i * 256 + tid;
            int row = f >> 3, s = f & 7;
            int cg = s ^ (row & 7);
            load_lds16(A + (size_t)(bm0 + row) * K + k0 + cg * 8, As + f * 8);
        }
        #pragma unroll
        for (int i = 0; i < 4; i++) {
            int f = i * 256 + tid;
            int col = f >> 3, s = f & 7;
            int cg = s ^ (col & 7);
            load_lds16(Bt + (size_t)(bn0 + col) * K + k0 + cg * 8, Bs + f * 8);
        }
        __syncthreads();
        #pragma unroll
        for (int ki = 0; ki < 64; ki += 32) {
            int kch = quad + (ki >> 3);
            int slot = kch ^ rxor;
            short8 af[4], bf[4];
            #pragma unroll
            for (int mi = 0; mi < 4; mi++)
                af[mi] = *(const short8*)(As + (rw + mi * 16 + l16) * 64 + slot * 8);
            #pragma unroll
            for (int ni = 0; ni < 4; ni++)
                bf[ni] = *(const short8*)(Bs + (cw + ni * 16 + l16) * 64 + slot * 8);
            #pragma unroll
            for (int mi = 0; mi < 4; mi++)
                #pragma unroll
                for (int ni = 0; ni < 4; ni++)
                    acc[mi][ni] = __builtin_amdgcn_mfma_f32_16x16x32_bf16(
                        af[mi], bf[ni], acc[mi][ni], 0, 0, 0);
        }
        __syncthreads();
    }

    // ---- epilogue: two 64-row half-tiles through 17.4KB of the LDS ----
    #pragma unroll
    for (int hp = 0; hp < 2; hp++) {
        if ((wave >> 1) == hp) {
            #pragma unroll
            for (int ni = 0; ni < 4; ni++) {
                int col = cw + ni * 16 + l16;
                int seg = col >> (SEGL2 + 1);
                int lr = (col >> SEGL2) & 1;
                int cc2 = col & ((1 << SEGL2) - 1);
                float bv = (lr ? rb : lb)[(seg << SEGL2) + cc2];
                #pragma unroll
                for (int mi = 0; mi < 4; mi++) {
                    int lrow = mi * 16 + quad * 4;        // 0..63 local
                    #pragma unroll
                    for (int i = 0; i < 4; i++) {
                        float v = acc[mi][ni][i] + bv;
                        if (ACT == 1) v = v > 0.f ? v : expm1f(v);
                        smem[(lrow + i) * 136 + col] = f2b(v);
                    }
                }
            }
        }
        __syncthreads();
        #pragma unroll
        for (int it = 0; it < 4; it++) {
            int chunk = it * 256 + tid;                   // 1024 chunks/half
            int row = chunk >> 4, cc = chunk & 15;
            int grow = bm0 + hp * 64 + row;
            if (grow < M) {
                u32x4 d = *(const u32x4*)(smem + row * 136 + cc * 8);
                __builtin_nontemporal_store(
                    d, (u32x4*)(Cb + (size_t)grow * N + bn0 + cc * 8));
            }
        }
        __syncthreads();
    }
}

// ---------------------------------------------------------------------------
// Fused layer 0/1: 2 waves per node (4 heads each), depth-2 prefetch,
// no-max softmax, fma-abs leaky. C layout [NN][3072] = et: XL(512)|XR(512).
// ---------------------------------------------------------------------------
__global__ __launch_bounds__(256)
void gat_fused01_k(const unsigned short* __restrict__ C,
                   const int* __restrict__ offs3,
                   const int* __restrict__ srcs3,
                   const float* __restrict__ att,     // [3][512]
                   const float* __restrict__ bias3,   // [3][512]
                   unsigned short* __restrict__ hb,   // in/out
                   const float* __restrict__ gamma,
                   const float* __restrict__ beta,
                   int n_nodes) {
    const unsigned LD = 3072;
    __shared__ float red[4][2];
    int tid = threadIdx.x;
    int lane = tid & 63, wave = tid >> 6;       // 0..3
    int half = wave & 1;
    int n = blockIdx.x * 2 + (wave >> 1);
    int c0 = half * 256 + lane * 4;             // this wave's 256-ch half
    float tot[4] = {0.f, 0.f, 0.f, 0.f};

    #pragma unroll
    for (int et = 0; et < 3; et++) {
        const int* offs = offs3 + et * (NN + 1);
        const int* srcs = srcs3 + (size_t)et * NE;
        int e0 = offs[n], e1 = offs[n + 1];
        if (e0 == e1) continue;
        const unsigned short* XL = C + et * 1024 + c0;
        float xr[4], c1[4], c2[4];
        {
            short4v t = *(const short4v*)(C + (size_t)n * LD + et * 1024 + 512 + c0);
            #pragma unroll
            for (int j = 0; j < 4; j++) xr[j] = b2f((unsigned short)t[j]);
            #pragma unroll
            for (int j = 0; j < 4; j++) {
                float a = att[et * 512 + c0 + j];
                c1[j] = 0.6f * a;               // leaky(v)=0.6v+0.4|v|
                c2[j] = 0.4f * a;
            }
        }
        float z = 0.f, acc[4] = {0.f, 0.f, 0.f, 0.f};
        short4v p0 = *(const short4v*)(XL + (unsigned)srcs[e0] * LD);
        short4v p1 = (e0 + 1 < e1) ? *(const short4v*)(XL + (unsigned)srcs[e0 + 1] * LD) : p0;
        for (int e = e0; e < e1; e++) {
            short4v cur = p0;
            p0 = p1;
            if (e + 2 < e1) p1 = *(const short4v*)(XL + (unsigned)srcs[e + 2] * LD);
            float xl[4];
            #pragma unroll
            for (int j = 0; j < 4; j++) xl[j] = b2f((unsigned short)cur[j]);
            float p = 0.f;
            #pragma unroll
            for (int j = 0; j < 4; j++) {
                float v = xl[j] + xr[j];
                p += c1[j] * v + c2[j] * __builtin_fabsf(v);   // abs = free modifier
            }
            p += __shfl_xor(p, 1, 64);          // head = 16-lane group
            p += __shfl_xor(p, 2, 64);
            p += __shfl_xor(p, 4, 64);
            p += __shfl_xor(p, 8, 64);
            float wgt = __expf(p);              // no-max: sigma(p)~3, safe
            z += wgt;
            #pragma unroll
            for (int j = 0; j < 4; j++) acc[j] += wgt * xl[j];
        }
        float inv = 1.f / z;
        #pragma unroll
        for (int j = 0; j < 4; j++) tot[j] += acc[j] * inv;
    }

    // finalize: bias + ELU + residual + LN (stats across the wave pair)
    unsigned short* hrow = hb + (size_t)n * DH + c0;
    float v[4]; float s1 = 0.f;
    {
        short4v rt = *(const short4v*)hrow;
        #pragma unroll
        for (int j = 0; j < 4; j++) {
            int c = c0 + j;
            float x = tot[j] + bias3[c] + bias3[512 + c] + bias3[1024 + c];
            x = x > 0.f ? x : expm1f(x);
            x += b2f((unsigned short)rt[j]);
            v[j] = x; s1 += x;
        }
    }
    #pragma unroll
    for (int off = 1; off < 64; off <<= 1) s1 += __shfl_xor(s1, off, 64);
    if (lane == 0) red[wave][0] = s1;
    __syncthreads();
    float s1full = s1 + red[wave ^ 1][0];
    float mean = s1full * (1.f / DH);
    float s2 = 0.f;
    #pragma unroll
    for (int j = 0; j < 4; j++) { float d = v[j] - mean; s2 += d * d; }
    #pragma unroll
    for (int off = 1; off < 64; off <<= 1) s2 += __shfl_xor(s2, off, 64);
    if (lane == 0) red[wave][1] = s2;
    __syncthreads();
    float s2full = s2 + red[wave ^ 1][1];
    float rstd = rsqrtf(s2full * (1.f / DH) + 1e-5f);
    unsigned short ov[4];
    #pragma unroll
    for (int j = 0; j < 4; j++) {
        int c = c0 + j;
        ov[j] = f2b((v[j] - mean) * rstd * gamma[c] + beta[c]);
    }
    *(short4v*)hrow = (short4v){(short)ov[0], (short)ov[1], (short)ov[2], (short)ov[3]};
}

// ---------------------------------------------------------------------------
// Fused layer 2: one wave per node, 256 ch, depth-2 prefetch, no-max softmax,
// fma-abs leaky. C layout [NN][1536] = et: XL(256)|XR(256).
// ---------------------------------------------------------------------------
__global__ void gat_fused2_k(const unsigned short* __restrict__ C,
                             const int* __restrict__ offs3,
                             const int* __restrict__ srcs3,
                             const float* __restrict__ att,     // [3][256]
                             const float* __restrict__ bias3,   // [3][256]
                             const float* __restrict__ gamma,
                             const float* __restrict__ beta,
                             float* __restrict__ out, int n_nodes) {
    const unsigned LD = 1536;
    int lane = threadIdx.x & 63;
    int n = blockIdx.x * (blockDim.x >> 6) + (threadIdx.x >> 6);
    if (n >= n_nodes) return;
    int c0 = lane * 4;
    float tot[4] = {0.f, 0.f, 0.f, 0.f};

    #pragma unroll
    for (int et = 0; et < 3; et++) {
        const int* offs = offs3 + et * (NN + 1);
        const int* srcs = srcs3 + (size_t)et * NE;
        int e0 = offs[n], e1 = offs[n + 1];
        if (e0 == e1) continue;
        const unsigned short* XL = C + et * 512 + c0;
        float xr[4], c1[4], c2[4];
        {
            short4v t = *(const short4v*)(C + (size_t)n * LD + et * 512 + 256 + c0);
            #pragma unroll
            for (int j = 0; j < 4; j++) xr[j] = b2f((unsigned short)t[j]);
            #pragma unroll
            for (int j = 0; j < 4; j++) {
                float a = att[et * 256 + c0 + j];
                c1[j] = 0.6f * a;
                c2[j] = 0.4f * a;
            }
        }
        float z = 0.f, acc[4] = {0.f, 0.f, 0.f, 0.f};
        short4v p0 = *(const short4v*)(XL + (unsigned)srcs[e0] * LD);
        short4v p1 = (e0 + 1 < e1) ? *(const short4v*)(XL + (unsigned)srcs[e0 + 1] * LD) : p0;
        for (int e = e0; e < e1; e++) {
            short4v cur = p0;
            p0 = p1;
            if (e + 2 < e1) p1 = *(const short4v*)(XL + (unsigned)srcs[e + 2] * LD);
            float xl[4];
            #pragma unroll
            for (int j = 0; j < 4; j++) xl[j] = b2f((unsigned short)cur[j]);
            float p = 0.f;
            #pragma unroll
            for (int j = 0; j < 4; j++) {
                float v = xl[j] + xr[j];
                p += c1[j] * v + c2[j] * __builtin_fabsf(v);
            }
            #pragma unroll
            for (int off = 1; off < 64; off <<= 1) p += __shfl_xor(p, off, 64);
            float wgt = __expf(p);
            z += wgt;
            #pragma unroll
            for (int j = 0; j < 4; j++) acc[j] += wgt * xl[j];
        }
        float inv = 1.f / z;
        #pragma unroll
        for (int j = 0; j < 4; j++) tot[j] += acc[j] * inv;
    }

    float v[4]; float s1 = 0.f;
    #pragma unroll
    for (int j = 0; j < 4; j++) {
        int c = c0 + j;
        float x = tot[j] + bias3[c] + bias3[256 + c] + bias3[512 + c];
        x = x > 0.f ? x : expm1f(x);
        v[j] = x; s1 += x;
    }
    #pragma unroll
    for (int off = 1; off < 64; off <<= 1) s1 += __shfl_xor(s1, off, 64);
    float mean = s1 * (1.f / DOUT);
    float s2 = 0.f;
    #pragma unroll
    for (int j = 0; j < 4; j++) { float d = v[j] - mean; s2 += d * d; }
    #pragma unroll
    for (int off = 1; off < 64; off <<= 1) s2 += __shfl_xor(s2, off, 64);
    float rstd = rsqrtf(s2 * (1.f / DOUT) + 1e-5f);
    #pragma unroll
    for (int j = 0; j < 4; j++) {
        int c = c0 + j;
        out[(size_t)n * DOUT + c] = (v[j] - mean) * rstd * gamma[c] + beta[c];
    }
}

// ---------------------------------------------------------------------------
extern "C" void kernel_launch(void* const* d_in, const int* in_sizes, int n_in,
                              void* d_out, int out_size, void* d_ws, size_t ws_size,
                              hipStream_t stream) {
    const float* x       = (const float*)d_in[0];
    const int*   ei      = (const int*)d_in[1];
    const float* proj_w  = (const float*)d_in[2];
    const float* proj_b  = (const float*)d_in[3];
    const float* l01lw   = (const float*)d_in[4];
    const float* l01lb   = (const float*)d_in[5];
    const float* l01rw   = (const float*)d_in[6];
    const float* l01rb   = (const float*)d_in[7];
    const float* l01att  = (const float*)d_in[8];
    const float* l01bias = (const float*)d_in[9];
    const float* l2lw    = (const float*)d_in[10];
    const float* l2lb    = (const float*)d_in[11];
    const float* l2rw    = (const float*)d_in[12];
    const float* l2rb    = (const float*)d_in[13];
    const float* l2att   = (const float*)d_in[14];
    const float* l2bias  = (const float*)d_in[15];
    const float* g01     = (const float*)d_in[16];
    const float* b01     = (const float*)d_in[17];
    const float* g2      = (const float*)d_in[18];
    const float* b2      = (const float*)d_in[19];
    (void)in_sizes; (void)n_in; (void)out_size; (void)ws_size;

    // ---- workspace layout ----
    char* w = (char*)d_ws;
    size_t off = 0;
    auto carve = [&](size_t bytes) { void* p = w + off; off = (off + bytes + 255) & ~(size_t)255; return p; };
    unsigned short* h_b     = (unsigned short*)carve((size_t)NN * DH * 2);       // 20.5 MB
    unsigned short* xb      = (unsigned short*)carve((size_t)NN * DH * 2);       // 20.5 MB
    unsigned short* Cbuf    = (unsigned short*)carve((size_t)NN * 3072 * 2);     // 123 MB
    unsigned short* Wt      = (unsigned short*)carve((size_t)4194304 * 2);       // 8.4 MB
    int*            counts3 = (int*)           carve((size_t)3 * (NN + 1) * 4);
    int*            offs3   = (int*)           carve((size_t)3 * (NN + 1) * 4);
    int*            cur3    = (int*)           carve((size_t)3 * (NN + 1) * 4);
    int*            srcs3   = (int*)           carve((size_t)3 * NE * 4);
    carve(65536);   // guard

    unsigned short* Wt_proj = Wt;                        // 512 x 512
    unsigned short* Wt_L0   = Wt_proj + 262144;          // 3072 x 512
    unsigned short* Wt_L1   = Wt_L0 + 3072 * 512;        // 3072 x 512
    unsigned short* Wt_L2   = Wt_L1 + 3072 * 512;        // 1536 x 512

    dim3 tb(256);
    const int MT = (NN + 127) / 128;     // 157
    const int STRIPE = (MT + 7) / 8;     // 20

    // ---- convert x; transpose+cast all 19 weight matrices in ONE launch ----
    cvt_f2b_k<<<dim3(5000), tb, 0, stream>>>(x, xb, NN * DH);
    TTable tt;
    {
        int s = 0;
        tt.s[s++] = {proj_w, Wt_proj, 512};
        for (int li = 0; li < 2; li++) {
            unsigned short* base = li ? Wt_L1 : Wt_L0;
            for (int et = 0; et < 3; et++)
                tt.s[s++] = {l01lw + (size_t)(li * 3 + et) * 262144,
                             base + (size_t)et * 2 * 262144, 512};
            for (int et = 0; et < 3; et++)
                tt.s[s++] = {l01rw + (size_t)(li * 3 + et) * 262144,
                             base + 262144 + (size_t)et * 2 * 262144, 512};
        }
        for (int et = 0; et < 3; et++)
            tt.s[s++] = {l2lw + (size_t)et * 131072,
                         Wt_L2 + (size_t)et * 2 * 131072, 256};
        for (int et = 0; et < 3; et++)
            tt.s[s++] = {l2rw + (size_t)et * 131072,
                         Wt_L2 + 131072 + (size_t)et * 2 * 131072, 256};
    }
    transpose_all_k<<<dim3(256, 19), tb, 0, stream>>>(tt);

    // ---- CSR build (merged; scan emits offs + cursor, no memcpy) ----
    hipMemsetAsync(counts3, 0, (size_t)3 * (NN + 1) * 4, stream);
    count_all_k<<<dim3((3 * NE + 255) / 256), tb, 0, stream>>>(ei, counts3);
    scan_par_k<<<dim3(3), dim3(1024), 0, stream>>>(counts3, offs3, cur3, NN);
    scatter_all_k<<<dim3((3 * NE + 255) / 256), tb, 0, stream>>>(ei, cur3, srcs3);

    // ---- input projection + ELU -> h_b ----
    gemm_k<1, 9><<<dim3(8 * STRIPE * 4), tb, 0, stream>>>(
        xb, Wt_proj, proj_b, proj_b, h_b, NN, 512, 512, MT, 4, STRIPE);

    // ---- layers 0, 1: merged GEMM (N=3072) + fused GAT/finalize ----
    for (int li = 0; li < 2; li++) {
        gemm_k<0, 9><<<dim3(8 * STRIPE * 24), tb, 0, stream>>>(
            h_b, li ? Wt_L1 : Wt_L0,
            l01lb + (size_t)li * 3 * 512, l01rb + (size_t)li * 3 * 512,
            Cbuf, NN, 3072, 512, MT, 24, STRIPE);
        gat_fused01_k<<<dim3(NN / 2), tb, 0, stream>>>(
            Cbuf, offs3, srcs3,
            l01att + (size_t)li * 3 * 512, l01bias + (size_t)li * 3 * 512,
            h_b, g01 + (size_t)li * DH, b01 + (size_t)li * DH, NN);
    }

    // ---- layer 2: merged GEMM (N=1536) + fused GAT/LN -> d_out ----
    gemm_k<0, 8><<<dim3(8 * STRIPE * 12), tb, 0, stream>>>(
        h_b, Wt_L2, l2lb, l2rb, Cbuf, NN, 1536, 512, MT, 12, STRIPE);
    gat_fused2_k<<<dim3(NN / 4), tb, 0, stream>>>(
        Cbuf, offs3, srcs3, l2att, l2bias, g2, b2, (float*)d_out, NN);
}

// Round 15
// 677.332 us; speedup vs baseline: 1.1889x; 1.1889x over previous
//
#include <hip/hip_runtime.h>

// ---------------------------------------------------------------------------
// HeteroGATv2Encoder on MI355X (gfx950).
// fp32 in / fp32 out. Merged per-layer bf16 MFMA GEMM (XCD swizzle, LDS XOR
// swizzle, LDS-staged coalesced epilogue). CSR edges + fused per-node GAT
// kernels (2 waves/node, depth-2 prefetch, no-max softmax, fma-abs leaky).
// R14 NT-store experiment reverted: L2-allocated C stores are a net win
// (write-back overlaps later kernels; NT forces a synchronous HBM drain).
// ---------------------------------------------------------------------------

#define NN 20000      // nodes
#define NE 100000     // edges per relation
#define DH 512        // hidden width (8 heads x 64)
#define DOUT 256

typedef __attribute__((ext_vector_type(8))) short short8;
typedef __attribute__((ext_vector_type(4))) short short4v;
typedef __attribute__((ext_vector_type(4))) float f32x4;

__device__ __forceinline__ float b2f(unsigned short s) {
    union { unsigned u; float f; } v; v.u = ((unsigned)s) << 16; return v.f;
}
__device__ __forceinline__ unsigned short f2b(float f) {
    unsigned u = __float_as_uint(f);
    u += 0x7FFFu + ((u >> 16) & 1u);   // RNE
    return (unsigned short)(u >> 16);
}
__device__ __forceinline__ void load_lds16(const unsigned short* g, unsigned short* l) {
    __builtin_amdgcn_global_load_lds(
        (const __attribute__((address_space(1))) unsigned int*)g,
        (__attribute__((address_space(3))) unsigned int*)l, 16, 0, 0);
}

// ---------------------------------------------------------------------------
__global__ void cvt_f2b_k(const float* __restrict__ in,
                          unsigned short* __restrict__ out, int n) {
    int i0 = (blockIdx.x * blockDim.x + threadIdx.x) * 8;
    if (i0 >= n) return;
    #pragma unroll
    for (int j = 0; j < 8; j++) out[i0 + j] = f2b(in[i0 + j]);
}

// ---------------------------------------------------------------------------
// Merged transpose+cast: 19 weight matrices in one launch.
// ---------------------------------------------------------------------------
struct TSeg { const float* in; unsigned short* out; int C; };
struct TTable { TSeg s[19]; };

__global__ void transpose_all_k(TTable t) {
    __shared__ float tile[32][33];
    TSeg d = t.s[blockIdx.y];
    int tiles_x = d.C >> 5;
    int nt = tiles_x << 4;
    if ((int)blockIdx.x >= nt) return;
    int bx = blockIdx.x % tiles_x, by = blockIdx.x / tiles_x;
    int c0 = bx * 32, r0 = by * 32;
    int tx = threadIdx.x & 31, ty = threadIdx.x >> 5;
    #pragma unroll
    for (int i = ty; i < 32; i += 8)
        tile[i][tx] = d.in[(size_t)(r0 + i) * d.C + c0 + tx];
    __syncthreads();
    #pragma unroll
    for (int i = ty; i < 32; i += 8)
        d.out[(size_t)(c0 + i) * 512 + r0 + tx] = f2b(tile[tx][i]);
}

// ---------------------------------------------------------------------------
// CSR build (merged over the 3 relations)
// ---------------------------------------------------------------------------
__global__ void count_all_k(const int* __restrict__ ei, int* __restrict__ counts) {
    int i = blockIdx.x * blockDim.x + threadIdx.x;
    if (i >= 3 * NE) return;
    int et = i / NE, idx = i - et * NE;
    int d = ei[(size_t)et * 2 * NE + NE + idx];
    atomicAdd(&counts[et * (NN + 1) + d], 1);
}

__global__ __launch_bounds__(1024)
void scan_par_k(const int* __restrict__ counts, int* __restrict__ offs,
                int* __restrict__ cursor, int n) {
    __shared__ int part[1024];
    const int* c = counts + (size_t)blockIdx.x * (n + 1);
    int* o = offs + (size_t)blockIdx.x * (n + 1);
    int* cu = cursor + (size_t)blockIdx.x * (n + 1);
    int tid = threadIdx.x;
    int per = (n + 1023) / 1024;
    int base = tid * per;
    int lim = min(base + per, n);
    int sum = 0;
    for (int i = base; i < lim; i++) sum += c[i];
    part[tid] = sum;
    __syncthreads();
    #pragma unroll
    for (int off = 1; off < 1024; off <<= 1) {
        int v = (tid >= off) ? part[tid - off] : 0;
        __syncthreads();
        part[tid] += v;
        __syncthreads();
    }
    int run = part[tid] - sum;
    for (int i = base; i < lim; i++) { o[i] = run; cu[i] = run; run += c[i]; }
    if (tid == 1023) { o[n] = part[1023]; cu[n] = part[1023]; }
}

__global__ void scatter_all_k(const int* __restrict__ ei, int* __restrict__ cursor,
                              int* __restrict__ srcs_sorted) {
    int i = blockIdx.x * blockDim.x + threadIdx.x;
    if (i >= 3 * NE) return;
    int et = i / NE, idx = i - et * NE;
    int s = ei[(size_t)et * 2 * NE + idx];
    int d = ei[(size_t)et * 2 * NE + NE + idx];
    int p = atomicAdd(&cursor[et * (NN + 1) + d], 1);
    srcs_sorted[(size_t)et * NE + p] = s;
}

// ---------------------------------------------------------------------------
// Tiled GEMM: XCD swizzle + XOR-swizzled LDS + LDS-staged coalesced epilogue.
// (R13 form — best measured: ~105 us at N=3072.)
// ---------------------------------------------------------------------------
template<int ACT, int SEGL2>
__global__ __launch_bounds__(256)
void gemm_k(const unsigned short* __restrict__ A,
            const unsigned short* __restrict__ Bt,
            const float* __restrict__ lb,
            const float* __restrict__ rb,
            unsigned short* __restrict__ Cb,
            int M, int N, int K, int MT, int NT, int STRIPE) {
    __shared__ __align__(16) unsigned short smem[17408];   // 34.8 KB
    unsigned short* As = smem;           // 128*64
    unsigned short* Bs = smem + 8192;    // 128*64
    int bid = blockIdx.x;
    int xcd = bid & 7, r = bid >> 3;
    int mtile = xcd * STRIPE + r / NT;
    int ntile = r % NT;
    if (mtile >= MT) return;
    int bm0 = mtile * 128, bn0 = ntile * 128;

    int tid = threadIdx.x;
    int lane = tid & 63, wave = tid >> 6;
    int quad = lane >> 4, l16 = lane & 15;
    int rw = (wave >> 1) * 64, cw = (wave & 1) * 64;
    int rxor = l16 & 7;

    f32x4 acc[4][4];
    #pragma unroll
    for (int mi = 0; mi < 4; mi++)
        #pragma unroll
        for (int ni = 0; ni < 4; ni++) acc[mi][ni] = (f32x4){0.f, 0.f, 0.f, 0.f};

    for (int k0 = 0; k0 < K; k0 += 64) {
        #pragma unroll
        for (int i = 0; i < 4; i++) {
            int f = i * 256 + tid;
            int row = f >> 3, s = f & 7;
            int cg = s ^ (row & 7);
            load_lds16(A + (size_t)(bm0 + row) * K + k0 + cg * 8, As + f * 8);
        }
        #pragma unroll
        for (int i = 0; i < 4; i++) {
            int f = i * 256 + tid;
            int col = f >> 3, s = f & 7;
            int cg = s ^ (col & 7);
            load_lds16(Bt + (size_t)(bn0 + col) * K + k0 + cg * 8, Bs + f * 8);
        }
        __syncthreads();
        #pragma unroll
        for (int ki = 0; ki < 64; ki += 32) {
            int kch = quad + (ki >> 3);
            int slot = kch ^ rxor;
            short8 af[4], bf[4];
            #pragma unroll
            for (int mi = 0; mi < 4; mi++)
                af[mi] = *(const short8*)(As + (rw + mi * 16 + l16) * 64 + slot * 8);
            #pragma unroll
            for (int ni = 0; ni < 4; ni++)
                bf[ni] = *(const short8*)(Bs + (cw + ni * 16 + l16) * 64 + slot * 8);
            #pragma unroll
            for (int mi = 0; mi < 4; mi++)
                #pragma unroll
                for (int ni = 0; ni < 4; ni++)
                    acc[mi][ni] = __builtin_amdgcn_mfma_f32_16x16x32_bf16(
                        af[mi], bf[ni], acc[mi][ni], 0, 0, 0);
        }
        __syncthreads();
    }

    // ---- epilogue: bias(+ELU) -> bf16 tile in LDS (stride 136) ----
    #pragma unroll
    for (int ni = 0; ni < 4; ni++) {
        int col = cw + ni * 16 + l16;
        int seg = col >> (SEGL2 + 1);
        int lr = (col >> SEGL2) & 1;
        int cc2 = col & ((1 << SEGL2) - 1);
        float bv = (lr ? rb : lb)[(seg << SEGL2) + cc2];
        #pragma unroll
        for (int mi = 0; mi < 4; mi++) {
            int row = rw + mi * 16 + quad * 4;
            #pragma unroll
            for (int i = 0; i < 4; i++) {
                float v = acc[mi][ni][i] + bv;
                if (ACT == 1) v = v > 0.f ? v : expm1f(v);
                smem[(row + i) * 136 + col] = f2b(v);
            }
        }
    }
    __syncthreads();
    #pragma unroll
    for (int it = 0; it < 8; it++) {
        int chunk = it * 256 + tid;
        int row = chunk >> 4, cc = chunk & 15;
        int grow = bm0 + row;
        if (grow < M) {
            uint4 d = *(const uint4*)(smem + row * 136 + cc * 8);
            *(uint4*)(Cb + (size_t)grow * N + bn0 + cc * 8) = d;
        }
    }
}

// ---------------------------------------------------------------------------
// Fused layer 0/1: 2 waves per node (4 heads each), depth-2 prefetch,
// no-max softmax, fma-abs leaky. C layout [NN][3072] = et: XL(512)|XR(512).
// ---------------------------------------------------------------------------
__global__ __launch_bounds__(256)
void gat_fused01_k(const unsigned short* __restrict__ C,
                   const int* __restrict__ offs3,
                   const int* __restrict__ srcs3,
                   const float* __restrict__ att,     // [3][512]
                   const float* __restrict__ bias3,   // [3][512]
                   unsigned short* __restrict__ hb,   // in/out
                   const float* __restrict__ gamma,
                   const float* __restrict__ beta,
                   int n_nodes) {
    const unsigned LD = 3072;
    __shared__ float red[4][2];
    int tid = threadIdx.x;
    int lane = tid & 63, wave = tid >> 6;       // 0..3
    int half = wave & 1;
    int n = blockIdx.x * 2 + (wave >> 1);
    int c0 = half * 256 + lane * 4;             // this wave's 256-ch half
    float tot[4] = {0.f, 0.f, 0.f, 0.f};

    #pragma unroll
    for (int et = 0; et < 3; et++) {
        const int* offs = offs3 + et * (NN + 1);
        const int* srcs = srcs3 + (size_t)et * NE;
        int e0 = offs[n], e1 = offs[n + 1];
        if (e0 == e1) continue;
        const unsigned short* XL = C + et * 1024 + c0;
        float xr[4], c1[4], c2[4];
        {
            short4v t = *(const short4v*)(C + (size_t)n * LD + et * 1024 + 512 + c0);
            #pragma unroll
            for (int j = 0; j < 4; j++) xr[j] = b2f((unsigned short)t[j]);
            #pragma unroll
            for (int j = 0; j < 4; j++) {
                float a = att[et * 512 + c0 + j];
                c1[j] = 0.6f * a;               // leaky(v)=0.6v+0.4|v|
                c2[j] = 0.4f * a;
            }
        }
        float z = 0.f, acc[4] = {0.f, 0.f, 0.f, 0.f};
        short4v p0 = *(const short4v*)(XL + (unsigned)srcs[e0] * LD);
        short4v p1 = (e0 + 1 < e1) ? *(const short4v*)(XL + (unsigned)srcs[e0 + 1] * LD) : p0;
        for (int e = e0; e < e1; e++) {
            short4v cur = p0;
            p0 = p1;
            if (e + 2 < e1) p1 = *(const short4v*)(XL + (unsigned)srcs[e + 2] * LD);
            float xl[4];
            #pragma unroll
            for (int j = 0; j < 4; j++) xl[j] = b2f((unsigned short)cur[j]);
            float p = 0.f;
            #pragma unroll
            for (int j = 0; j < 4; j++) {
                float v = xl[j] + xr[j];
                p += c1[j] * v + c2[j] * __builtin_fabsf(v);   // abs = free modifier
            }
            p += __shfl_xor(p, 1, 64);          // head = 16-lane group
            p += __shfl_xor(p, 2, 64);
            p += __shfl_xor(p, 4, 64);
            p += __shfl_xor(p, 8, 64);
            float wgt = __expf(p);              // no-max: sigma(p)~3, safe
            z += wgt;
            #pragma unroll
            for (int j = 0; j < 4; j++) acc[j] += wgt * xl[j];
        }
        float inv = 1.f / z;
        #pragma unroll
        for (int j = 0; j < 4; j++) tot[j] += acc[j] * inv;
    }

    // finalize: bias + ELU + residual + LN (stats across the wave pair)
    unsigned short* hrow = hb + (size_t)n * DH + c0;
    float v[4]; float s1 = 0.f;
    {
        short4v rt = *(const short4v*)hrow;
        #pragma unroll
        for (int j = 0; j < 4; j++) {
            int c = c0 + j;
            float x = tot[j] + bias3[c] + bias3[512 + c] + bias3[1024 + c];
            x = x > 0.f ? x : expm1f(x);
            x += b2f((unsigned short)rt[j]);
            v[j] = x; s1 += x;
        }
    }
    #pragma unroll
    for (int off = 1; off < 64; off <<= 1) s1 += __shfl_xor(s1, off, 64);
    if (lane == 0) red[wave][0] = s1;
    __syncthreads();
    float s1full = s1 + red[wave ^ 1][0];
    float mean = s1full * (1.f / DH);
    float s2 = 0.f;
    #pragma unroll
    for (int j = 0; j < 4; j++) { float d = v[j] - mean; s2 += d * d; }
    #pragma unroll
    for (int off = 1; off < 64; off <<= 1) s2 += __shfl_xor(s2, off, 64);
    if (lane == 0) red[wave][1] = s2;
    __syncthreads();
    float s2full = s2 + red[wave ^ 1][1];
    float rstd = rsqrtf(s2full * (1.f / DH) + 1e-5f);
    unsigned short ov[4];
    #pragma unroll
    for (int j = 0; j < 4; j++) {
        int c = c0 + j;
        ov[j] = f2b((v[j] - mean) * rstd * gamma[c] + beta[c]);
    }
    *(short4v*)hrow = (short4v){(short)ov[0], (short)ov[1], (short)ov[2], (short)ov[3]};
}

// ---------------------------------------------------------------------------
// Fused layer 2: one wave per node, 256 ch, depth-2 prefetch, no-max softmax,
// fma-abs leaky. C layout [NN][1536] = et: XL(256)|XR(256).
// ---------------------------------------------------------------------------
__global__ void gat_fused2_k(const unsigned short* __restrict__ C,
                             const int* __restrict__ offs3,
                             const int* __restrict__ srcs3,
                             const float* __restrict__ att,     // [3][256]
                             const float* __restrict__ bias3,   // [3][256]
                             const float* __restrict__ gamma,
                             const float* __restrict__ beta,
                             float* __restrict__ out, int n_nodes) {
    const unsigned LD = 1536;
    int lane = threadIdx.x & 63;
    int n = blockIdx.x * (blockDim.x >> 6) + (threadIdx.x >> 6);
    if (n >= n_nodes) return;
    int c0 = lane * 4;
    float tot[4] = {0.f, 0.f, 0.f, 0.f};

    #pragma unroll
    for (int et = 0; et < 3; et++) {
        const int* offs = offs3 + et * (NN + 1);
        const int* srcs = srcs3 + (size_t)et * NE;
        int e0 = offs[n], e1 = offs[n + 1];
        if (e0 == e1) continue;
        const unsigned short* XL = C + et * 512 + c0;
        float xr[4], c1[4], c2[4];
        {
            short4v t = *(const short4v*)(C + (size_t)n * LD + et * 512 + 256 + c0);
            #pragma unroll
            for (int j = 0; j < 4; j++) xr[j] = b2f((unsigned short)t[j]);
            #pragma unroll
            for (int j = 0; j < 4; j++) {
                float a = att[et * 256 + c0 + j];
                c1[j] = 0.6f * a;
                c2[j] = 0.4f * a;
            }
        }
        float z = 0.f, acc[4] = {0.f, 0.f, 0.f, 0.f};
        short4v p0 = *(const short4v*)(XL + (unsigned)srcs[e0] * LD);
        short4v p1 = (e0 + 1 < e1) ? *(const short4v*)(XL + (unsigned)srcs[e0 + 1] * LD) : p0;
        for (int e = e0; e < e1; e++) {
            short4v cur = p0;
            p0 = p1;
            if (e + 2 < e1) p1 = *(const short4v*)(XL + (unsigned)srcs[e + 2] * LD);
            float xl[4];
            #pragma unroll
            for (int j = 0; j < 4; j++) xl[j] = b2f((unsigned short)cur[j]);
            float p = 0.f;
            #pragma unroll
            for (int j = 0; j < 4; j++) {
                float v = xl[j] + xr[j];
                p += c1[j] * v + c2[j] * __builtin_fabsf(v);
            }
            #pragma unroll
            for (int off = 1; off < 64; off <<= 1) p += __shfl_xor(p, off, 64);
            float wgt = __expf(p);
            z += wgt;
            #pragma unroll
            for (int j = 0; j < 4; j++) acc[j] += wgt * xl[j];
        }
        float inv = 1.f / z;
        #pragma unroll
        for (int j = 0; j < 4; j++) tot[j] += acc[j] * inv;
    }

    float v[4]; float s1 = 0.f;
    #pragma unroll
    for (int j = 0; j < 4; j++) {
        int c = c0 + j;
        float x = tot[j] + bias3[c] + bias3[256 + c] + bias3[512 + c];
        x = x > 0.f ? x : expm1f(x);
        v[j] = x; s1 += x;
    }
    #pragma unroll
    for (int off = 1; off < 64; off <<= 1) s1 += __shfl_xor(s1, off, 64);
    float mean = s1 * (1.f / DOUT);
    float s2 = 0.f;
    #pragma unroll
    for (int j = 0; j < 4; j++) { float d = v[j] - mean; s2 += d * d; }
    #pragma unroll
    for (int off = 1; off < 64; off <<= 1) s2 += __shfl_xor(s2, off, 64);
    float rstd = rsqrtf(s2 * (1.f / DOUT) + 1e-5f);
    #pragma unroll
    for (int j = 0; j < 4; j++) {
        int c = c0 + j;
        out[(size_t)n * DOUT + c] = (v[j] - mean) * rstd * gamma[c] + beta[c];
    }
}

// ---------------------------------------------------------------------------
extern "C" void kernel_launch(void* const* d_in, const int* in_sizes, int n_in,
                              void* d_out, int out_size, void* d_ws, size_t ws_size,
                              hipStream_t stream) {
    const float* x       = (const float*)d_in[0];
    const int*   ei      = (const int*)d_in[1];
    const float* proj_w  = (const float*)d_in[2];
    const float* proj_b  = (const float*)d_in[3];
    const float* l01lw   = (const float*)d_in[4];
    const float* l01lb   = (const float*)d_in[5];
    const float* l01rw   = (const float*)d_in[6];
    const float* l01rb   = (const float*)d_in[7];
    const float* l01att  = (const float*)d_in[8];
    const float* l01bias = (const float*)d_in[9];
    const float* l2lw    = (const float*)d_in[10];
    const float* l2lb    = (const float*)d_in[11];
    const float* l2rw    = (const float*)d_in[12];
    const float* l2rb    = (const float*)d_in[13];
    const float* l2att   = (const float*)d_in[14];
    const float* l2bias  = (const float*)d_in[15];
    const float* g01     = (const float*)d_in[16];
    const float* b01     = (const float*)d_in[17];
    const float* g2      = (const float*)d_in[18];
    const float* b2      = (const float*)d_in[19];
    (void)in_sizes; (void)n_in; (void)out_size; (void)ws_size;

    // ---- workspace layout ----
    char* w = (char*)d_ws;
    size_t off = 0;
    auto carve = [&](size_t bytes) { void* p = w + off; off = (off + bytes + 255) & ~(size_t)255; return p; };
    unsigned short* h_b     = (unsigned short*)carve((size_t)NN * DH * 2);       // 20.5 MB
    unsigned short* xb      = (unsigned short*)carve((size_t)NN * DH * 2);       // 20.5 MB
    unsigned short* Cbuf    = (unsigned short*)carve((size_t)NN * 3072 * 2);     // 123 MB
    unsigned short* Wt      = (unsigned short*)carve((size_t)4194304 * 2);       // 8.4 MB
    int*            counts3 = (int*)           carve((size_t)3 * (NN + 1) * 4);
    int*            offs3   = (int*)           carve((size_t)3 * (NN + 1) * 4);
    int*            cur3    = (int*)           carve((size_t)3 * (NN + 1) * 4);
    int*            srcs3   = (int*)           carve((size_t)3 * NE * 4);
    carve(65536);   // guard

    unsigned short* Wt_proj = Wt;                        // 512 x 512
    unsigned short* Wt_L0   = Wt_proj + 262144;          // 3072 x 512
    unsigned short* Wt_L1   = Wt_L0 + 3072 * 512;        // 3072 x 512
    unsigned short* Wt_L2   = Wt_L1 + 3072 * 512;        // 1536 x 512

    dim3 tb(256);
    const int MT = (NN + 127) / 128;     // 157
    const int STRIPE = (MT + 7) / 8;     // 20

    // ---- convert x; transpose+cast all 19 weight matrices in ONE launch ----
    cvt_f2b_k<<<dim3(5000), tb, 0, stream>>>(x, xb, NN * DH);
    TTable tt;
    {
        int s = 0;
        tt.s[s++] = {proj_w, Wt_proj, 512};
        for (int li = 0; li < 2; li++) {
            unsigned short* base = li ? Wt_L1 : Wt_L0;
            for (int et = 0; et < 3; et++)
                tt.s[s++] = {l01lw + (size_t)(li * 3 + et) * 262144,
                             base + (size_t)et * 2 * 262144, 512};
            for (int et = 0; et < 3; et++)
                tt.s[s++] = {l01rw + (size_t)(li * 3 + et) * 262144,
                             base + 262144 + (size_t)et * 2 * 262144, 512};
        }
        for (int et = 0; et < 3; et++)
            tt.s[s++] = {l2lw + (size_t)et * 131072,
                         Wt_L2 + (size_t)et * 2 * 131072, 256};
        for (int et = 0; et < 3; et++)
            tt.s[s++] = {l2rw + (size_t)et * 131072,
                         Wt_L2 + 131072 + (size_t)et * 2 * 131072, 256};
    }
    transpose_all_k<<<dim3(256, 19), tb, 0, stream>>>(tt);

    // ---- CSR build (merged; scan emits offs + cursor, no memcpy) ----
    hipMemsetAsync(counts3, 0, (size_t)3 * (NN + 1) * 4, stream);
    count_all_k<<<dim3((3 * NE + 255) / 256), tb, 0, stream>>>(ei, counts3);
    scan_par_k<<<dim3(3), dim3(1024), 0, stream>>>(counts3, offs3, cur3, NN);
    scatter_all_k<<<dim3((3 * NE + 255) / 256), tb, 0, stream>>>(ei, cur3, srcs3);

    // ---- input projection + ELU -> h_b ----
    gemm_k<1, 9><<<dim3(8 * STRIPE * 4), tb, 0, stream>>>(
        xb, Wt_proj, proj_b, proj_b, h_b, NN, 512, 512, MT, 4, STRIPE);

    // ---- layers 0, 1: merged GEMM (N=3072) + fused GAT/finalize ----
    for (int li = 0; li < 2; li++) {
        gemm_k<0, 9><<<dim3(8 * STRIPE * 24), tb, 0, stream>>>(
            h_b, li ? Wt_L1 : Wt_L0,
            l01lb + (size_t)li * 3 * 512, l01rb + (size_t)li * 3 * 512,
            Cbuf, NN, 3072, 512, MT, 24, STRIPE);
        gat_fused01_k<<<dim3(NN / 2), tb, 0, stream>>>(
            Cbuf, offs3, srcs3,
            l01att + (size_t)li * 3 * 512, l01bias + (size_t)li * 3 * 512,
            h_b, g01 + (size_t)li * DH, b01 + (size_t)li * DH, NN);
    }

    // ---- layer 2: merged GEMM (N=1536) + fused GAT/LN -> d_out ----
    gemm_k<0, 8><<<dim3(8 * STRIPE * 12), tb, 0, stream>>>(
        h_b, Wt_L2, l2lb, l2rb, Cbuf, NN, 1536, 512, MT, 12, STRIPE);
    gat_fused2_k<<<dim3(NN / 4), tb, 0, stream>>>(
        Cbuf, offs3, srcs3, l2att, l2bias, g2, b2, (float*)d_out, NN);
}